// Round 20
// baseline (438.330 us; speedup 1.0000x reference)
//
#include <hip/hip_runtime.h>
#include <hip/hip_bf16.h>
#include <stdint.h>

typedef __bf16 bf16_t;
typedef __bf16 bf16x8 __attribute__((ext_vector_type(8)));
typedef __bf16 bf16x4 __attribute__((ext_vector_type(4)));
typedef float f32x4 __attribute__((ext_vector_type(4)));
typedef uint32_t u32x2 __attribute__((ext_vector_type(2)));
typedef __attribute__((address_space(3))) const uint8_t* lds3;

#define T_TOK 4096
#define DIM   1024
#define HID   2048
#define NE    8
#define MAXT  72   // max 128-row m-tiles: 8192/128 + 8

// async global->LDS, 16B per lane, LDS dest = wave-uniform base + lane*16
__device__ __forceinline__ void gload_lds16(const void* g, void* l) {
  __builtin_amdgcn_global_load_lds(
      (const __attribute__((address_space(1))) unsigned int*)g,
      (__attribute__((address_space(3))) unsigned int*)l, 16, 0, 0);
}

// hardware transpose read (cross-lane; R19-validated): lane contributes 8B at its addr,
// 16-lane group assembles a 4x16 bf16 subtile; result lane l elem j = subtile[j][l&15].
#define TRR(dst, a, OFF) \
  asm volatile("ds_read_b64_tr_b16 %0, %1 offset:" OFF : "=v"(dst) : "v"(a))

__device__ __forceinline__ bf16x8 mk8(u32x2 lo, u32x2 hi) {
  uint4 t; t.x = lo[0]; t.y = lo[1]; t.z = hi[0]; t.w = hi[1];
  return __builtin_bit_cast(bf16x8, t);
}

__device__ __forceinline__ bf16x4 cvt4(float4 v) {
  bf16x4 o; o[0] = (bf16_t)v.x; o[1] = (bf16_t)v.y; o[2] = (bf16_t)v.z; o[3] = (bf16_t)v.w;
  return o;
}

// ---------------- router (+ fused x->bf16): logits, sigmoid, top-2, aux ----------------
__global__ __launch_bounds__(256) void k_router(const float* __restrict__ x,
    const float* __restrict__ rw, const float* __restrict__ rb,
    int* __restrict__ counts, int* __restrict__ top_i, float* __restrict__ top_w,
    float* __restrict__ aux, bf16_t* __restrict__ xb) {
  int t = blockIdx.x * 4 + (threadIdx.x >> 6);
  int lane = threadIdx.x & 63;
  const float* xt = x + (size_t)t * DIM;
  float acc[8] = {0.f,0.f,0.f,0.f,0.f,0.f,0.f,0.f};
#pragma unroll
  for (int it = 0; it < 4; ++it) {
    int i = (it * 64 + lane) * 4;
    float4 xv = *(const float4*)(xt + i);
    *(bf16x4*)(xb + (size_t)t * DIM + i) = cvt4(xv);
#pragma unroll
    for (int c = 0; c < 4; ++c) {
      float v = (c == 0) ? xv.x : (c == 1) ? xv.y : (c == 2) ? xv.z : xv.w;
      float4 r0 = *(const float4*)(rw + (size_t)(i + c) * 8);
      float4 r1 = *(const float4*)(rw + (size_t)(i + c) * 8 + 4);
      acc[0] += v * r0.x; acc[1] += v * r0.y; acc[2] += v * r0.z; acc[3] += v * r0.w;
      acc[4] += v * r1.x; acc[5] += v * r1.y; acc[6] += v * r1.z; acc[7] += v * r1.w;
    }
  }
#pragma unroll
  for (int m = 32; m >= 1; m >>= 1) {
#pragma unroll
    for (int e = 0; e < 8; ++e) acc[e] += __shfl_xor(acc[e], m, 64);
  }
  if (lane == 0) {
    float s[8]; float sumsq = 0.f;
#pragma unroll
    for (int e = 0; e < 8; ++e) {
      float lg = acc[e] + rb[e];
      sumsq += lg * lg;
      s[e] = 1.f / (1.f + __expf(-lg));
    }
    int i1 = 0;
#pragma unroll
    for (int e = 1; e < 8; ++e) if (s[e] > s[i1]) i1 = e;
    int i2 = (i1 == 0) ? 1 : 0;
#pragma unroll
    for (int e = 0; e < 8; ++e) if (e != i1 && s[e] > s[i2]) i2 = e;
    float v1 = s[i1], v2 = s[i2];
    float den = v1 + v2 + 1e-6f;
    top_i[2 * t]     = i1; top_i[2 * t + 1] = i2;
    top_w[2 * t]     = v1 / den;
    top_w[2 * t + 1] = v2 / den;
    atomicAdd(&counts[i1], 1);
    atomicAdd(&counts[i2], 1);
    atomicAdd(aux, 0.01f * sumsq * (1.f / 32768.f));
  }
}

// ---------------- plan: base offsets + m-tile table ----------------
__global__ void k_plan(const int* __restrict__ counts, int* __restrict__ base,
                       int* __restrict__ tile_e, int* __restrict__ tile_m0) {
  if (threadIdx.x == 0) {
    int s = 0, nt = 0;
    for (int e = 0; e < NE; ++e) {
      base[e] = s;
      int c = counts[e];
      for (int m0 = 0; m0 < c; m0 += 128) { tile_e[nt] = e; tile_m0[nt] = m0; ++nt; }
      s += c;
    }
    for (; nt < MAXT; ++nt) tile_e[nt] = -1;
  }
}

// ---------------- gather tokens into per-expert slot lists ----------------
__global__ __launch_bounds__(256) void k_gather(const int* __restrict__ top_i,
    const float* __restrict__ top_w, const int* __restrict__ base,
    int* __restrict__ fill, int* __restrict__ slot_token, float* __restrict__ slot_wt,
    int* __restrict__ slot_of) {
  int t = blockIdx.x * 256 + threadIdx.x;
  if (t >= T_TOK) return;
#pragma unroll
  for (int j = 0; j < 2; ++j) {
    int e = top_i[2 * t + j];
    int p = atomicAdd(&fill[e], 1);
    int g = base[e] + p;
    slot_token[g] = t;
    slot_wt[g]    = top_w[2 * t + j];
    slot_of[2 * t + j] = g;
  }
}

// ---------------- GEMM1 + SwiGLU: f32 weights read DIRECTLY, cvt during staging ----------------
// tile 128m x 64n (two panels). A: bf16 gload dbuf. B: f32->reg->cvt->ds_write_b64 into
// R19-validated [kb][nb][4][16] subtile layout, consumed by tr reads. LDS 48 KB.
__global__ __launch_bounds__(256) void k_gemm1(
    const bf16_t* __restrict__ xb, const float* __restrict__ w12,
    const int* __restrict__ counts, const int* __restrict__ base,
    const int* __restrict__ tile_e, const int* __restrict__ tile_m0,
    const int* __restrict__ slot_token, bf16_t* __restrict__ h) {
  const int e = tile_e[blockIdx.y];
  if (e < 0) return;
  const int m0  = tile_m0[blockIdx.y];
  const int cnt = counts[e];
  const int bas = base[e];
  const int n0  = blockIdx.x * 64;          // hid col base, [0,2048)
  const float* Wf1 = w12 + (size_t)e * (1024u * 4096u) + n0;  // [k][4096] f32 rows
  const float* Wf2 = Wf1 + 2048;

  __shared__ bf16_t sA[2][128 * 64];   // 32 KB
  __shared__ bf16_t sB1[64 * 64];      // 8 KB (single buffer)
  __shared__ bf16_t sB2[64 * 64];      // 8 KB

  const int tid = threadIdx.x, lane = tid & 63, wid = tid >> 6;
  const int wr = wid >> 1, wc = wid & 1;
  const int lr = lane >> 3, sw = (lane & 7) ^ lr;  // A swizzled source chunk

  int tokA[4];
#pragma unroll
  for (int i = 0; i < 4; ++i) {
    int row = m0 + wid * 32 + i * 8 + lr;
    tokA[i] = slot_token[bas + (row < cnt ? row : cnt - 1)];
  }

  // B write decode: thread covers (k = i*16 + krow, n4..n4+3), i=0..3
  const int krow = tid >> 4;         // 0..15
  const int n4l  = (tid & 15) * 4;   // 0..60
  const int wB = (krow >> 2) * 512 + (krow & 3) * 32
               + (n4l >> 4) * 128 + ((n4l >> 3) & 1) * 16 + (n4l & 7) * 2;
  // per-i byte = i*2048 + wB

  float4 b1r[4], b2r[4];

  auto issueA = [&](int p, int k0) {
#pragma unroll
    for (int i = 0; i < 4; ++i)
      gload_lds16(xb + (size_t)tokA[i] * DIM + k0 + sw * 8,
                  &sA[p][(wid * 32 + i * 8) * 64]);
  };
  auto issueB = [&](int k0) {
#pragma unroll
    for (int i = 0; i < 4; ++i) {
      size_t row = (size_t)(k0 + i * 16 + krow) * 4096 + n4l;
      b1r[i] = *(const float4*)(Wf1 + row);
      b2r[i] = *(const float4*)(Wf2 + row);
    }
  };
  auto writeB = [&]() {
    char* c1 = (char*)sB1, *c2 = (char*)sB2;
#pragma unroll
    for (int i = 0; i < 4; ++i) {
      *(bf16x4*)(c1 + i * 2048 + wB) = cvt4(b1r[i]);
      *(bf16x4*)(c2 + i * 2048 + wB) = cvt4(b2r[i]);
    }
  };

  // tr-read lane base: kk*4096 + (lane>>4)*1024 + wc*256 + (lane&15)*8  (R19-validated)
  const int trOff = (lane >> 4) * 1024 + wc * 256 + (lane & 15) * 8;
  lds3 bB1 = (lds3)(const uint8_t*)sB1;
  lds3 bB2 = (lds3)(const uint8_t*)sB2;

  f32x4 acc1[4][2] = {};
  f32x4 acc2[4][2] = {};

  issueA(0, 0); issueB(0);

  const int NT = DIM / 64;  // 16
  for (int t = 0; t < NT; ++t) {
    const int p = t & 1;
    asm volatile("s_waitcnt vmcnt(0)" ::: "memory");   // A(t) in sA[p]; Breg(t) valid
    writeB();
    __syncthreads();                                   // B writes visible; sA[p] ready
    if (t + 1 < NT) { issueA(p ^ 1, (t + 1) * 64); issueB((t + 1) * 64); }
    __builtin_amdgcn_s_setprio(1);
#pragma unroll
    for (int kk = 0; kk < 2; ++kk) {
      const int g = kk * 4 + (lane >> 4);
      bf16x8 a[4];
#pragma unroll
      for (int mf = 0; mf < 4; ++mf) {
        int r = wr * 64 + mf * 16 + (lane & 15);
        a[mf] = *(const bf16x8*)(&sA[p][r * 64 + ((g ^ (r & 7)) << 3)]);
      }
      lds3 a1 = bB1 + kk * 4096 + trOff;
      lds3 a2 = bB2 + kk * 4096 + trOff;
      u32x2 q0, q1, q2, q3, s0, s1, s2, s3;
      TRR(q0, a1, "0");   TRR(q1, a1, "512");
      TRR(q2, a1, "128"); TRR(q3, a1, "640");
      TRR(s0, a2, "0");   TRR(s1, a2, "512");
      TRR(s2, a2, "128"); TRR(s3, a2, "640");
      asm volatile("s_waitcnt lgkmcnt(0)" ::: "memory");
      __builtin_amdgcn_sched_barrier(0);
      bf16x8 b1f[2] = { mk8(q0, q1), mk8(q2, q3) };
      bf16x8 b2f[2] = { mk8(s0, s1), mk8(s2, s3) };
#pragma unroll
      for (int mf = 0; mf < 4; ++mf)
#pragma unroll
        for (int nf = 0; nf < 2; ++nf) {
          acc1[mf][nf] = __builtin_amdgcn_mfma_f32_16x16x32_bf16(a[mf], b1f[nf], acc1[mf][nf], 0, 0, 0);
          acc2[mf][nf] = __builtin_amdgcn_mfma_f32_16x16x32_bf16(a[mf], b2f[nf], acc2[mf][nf], 0, 0, 0);
        }
    }
    __builtin_amdgcn_s_setprio(0);
    __builtin_amdgcn_sched_barrier(0);
    __syncthreads();                                   // all reads of sB done before next writeB
  }

#pragma unroll
  for (int mf = 0; mf < 4; ++mf)
#pragma unroll
    for (int r = 0; r < 4; ++r) {
      int m = wr * 64 + mf * 16 + ((lane >> 4) << 2) + r;
      if (m0 + m < cnt) {
        size_t rowoff = (size_t)(bas + m0 + m) * HID + n0;
#pragma unroll
        for (int nf = 0; nf < 2; ++nf) {
          int col = wc * 32 + nf * 16 + (lane & 15);
          float d1 = acc1[mf][nf][r], d2 = acc2[mf][nf][r];
          h[rowoff + col] = (bf16_t)((d1 / (1.f + __expf(-d1))) * d2);
        }
      }
    }
}

// ---------------- GEMM2: eout = wt*(h @ W3), f32 w3 read directly ----------------
// tile 128m x 128n. A: h bf16 gload dbuf. B: f32->cvt->ds_write into [kb][nb 0..7][4][16].
__global__ __launch_bounds__(256) void k_gemm2(
    const bf16_t* __restrict__ h, const float* __restrict__ w3,
    const int* __restrict__ counts, const int* __restrict__ base,
    const int* __restrict__ tile_e, const int* __restrict__ tile_m0,
    const float* __restrict__ slot_wt, bf16_t* __restrict__ eout) {
  const int e = tile_e[blockIdx.y];
  if (e < 0) return;
  const int m0  = tile_m0[blockIdx.y];
  const int cnt = counts[e];
  const int bas = base[e];
  const int n0 = blockIdx.x * 128;
  const float* Wf = w3 + (size_t)e * (2048u * 1024u) + n0;   // [k][1024] f32 rows

  __shared__ bf16_t sA[2][128 * 64];   // 32 KB
  __shared__ bf16_t sB[128 * 64];      // 16 KB single buffer

  const int tid = threadIdx.x, lane = tid & 63, wid = tid >> 6;
  const int wr = wid >> 1, wc = wid & 1;
  const int lr = lane >> 3, sw = (lane & 7) ^ lr;

  int rowA[4];
#pragma unroll
  for (int i = 0; i < 4; ++i) {
    int row = m0 + wid * 32 + i * 8 + lr;
    rowA[i] = bas + (row < cnt ? row : cnt - 1);
  }

  // B write decode: thread covers (k = i*8 + krow2, n4..n4+3), i=0..7
  const int krow2 = tid >> 5;          // 0..7
  const int n4l2  = (tid & 31) * 4;    // 0..124
  const int wB2 = (krow2 >> 2) * 1024 + (krow2 & 3) * 32
                + (n4l2 >> 4) * 128 + ((n4l2 >> 3) & 1) * 16 + (n4l2 & 7) * 2;
  // per-i byte = i*2048 + wB2

  float4 br[8];

  auto issueA = [&](int p, int k0) {
#pragma unroll
    for (int i = 0; i < 4; ++i)
      gload_lds16(h + (size_t)rowA[i] * HID + k0 + sw * 8,
                  &sA[p][(wid * 32 + i * 8) * 64]);
  };
  auto issueB = [&](int k0) {
#pragma unroll
    for (int i = 0; i < 8; ++i)
      br[i] = *(const float4*)(Wf + (size_t)(k0 + i * 8 + krow2) * 1024 + n4l2);
  };
  auto writeB = [&]() {
    char* c = (char*)sB;
#pragma unroll
    for (int i = 0; i < 8; ++i)
      *(bf16x4*)(c + i * 2048 + wB2) = cvt4(br[i]);
  };

  // tr base: kk*8192 + (lane>>4)*2048 + wc*512 + (lane&15)*8
  const int trOff = (lane >> 4) * 2048 + wc * 512 + (lane & 15) * 8;
  lds3 bB = (lds3)(const uint8_t*)sB;

  f32x4 acc[4][4] = {};

  issueA(0, 0); issueB(0);

  const int NT = HID / 64;  // 32
  for (int t = 0; t < NT; ++t) {
    const int p = t & 1;
    asm volatile("s_waitcnt vmcnt(0)" ::: "memory");
    writeB();
    __syncthreads();
    if (t + 1 < NT) { issueA(p ^ 1, (t + 1) * 64); issueB((t + 1) * 64); }
    __builtin_amdgcn_s_setprio(1);
#pragma unroll
    for (int kk = 0; kk < 2; ++kk) {
      const int g = kk * 4 + (lane >> 4);
      bf16x8 a[4];
#pragma unroll
      for (int mf = 0; mf < 4; ++mf) {
        int r = wr * 64 + mf * 16 + (lane & 15);
        a[mf] = *(const bf16x8*)(&sA[p][r * 64 + ((g ^ (r & 7)) << 3)]);
      }
      lds3 ab = bB + kk * 8192 + trOff;
      u32x2 q0, q1, q2, q3, q4, q5, q6, q7;
      TRR(q0, ab, "0");   TRR(q1, ab, "1024");
      TRR(q2, ab, "128"); TRR(q3, ab, "1152");
      TRR(q4, ab, "256"); TRR(q5, ab, "1280");
      TRR(q6, ab, "384"); TRR(q7, ab, "1408");
      asm volatile("s_waitcnt lgkmcnt(0)" ::: "memory");
      __builtin_amdgcn_sched_barrier(0);
      bf16x8 bf[4] = { mk8(q0, q1), mk8(q2, q3), mk8(q4, q5), mk8(q6, q7) };
#pragma unroll
      for (int mf = 0; mf < 4; ++mf)
#pragma unroll
        for (int nf = 0; nf < 4; ++nf)
          acc[mf][nf] = __builtin_amdgcn_mfma_f32_16x16x32_bf16(a[mf], bf[nf], acc[mf][nf], 0, 0, 0);
    }
    __builtin_amdgcn_s_setprio(0);
    __builtin_amdgcn_sched_barrier(0);
    __syncthreads();
  }

#pragma unroll
  for (int mf = 0; mf < 4; ++mf)
#pragma unroll
    for (int r = 0; r < 4; ++r) {
      int m = wr * 64 + mf * 16 + ((lane >> 4) << 2) + r;
      if (m0 + m < cnt) {
        int gs = bas + m0 + m;
        float wt = slot_wt[gs];
        size_t o = (size_t)gs * DIM + n0;
#pragma unroll
        for (int nf = 0; nf < 4; ++nf) {
          int col = wc * 64 + nf * 16 + (lane & 15);
          eout[o + col] = (bf16_t)(acc[mf][nf][r] * wt);
        }
      }
    }
}

// ---------------- combine: out[t] = eout[g0] + eout[g1] ----------------
__global__ __launch_bounds__(256) void k_combine(const bf16_t* __restrict__ eout,
    const int* __restrict__ slot_of, float* __restrict__ out) {
  const int t = blockIdx.x;
  const int c = threadIdx.x * 4;
  const int g0 = slot_of[2 * t], g1 = slot_of[2 * t + 1];
  bf16x4 a = *(const bf16x4*)(eout + (size_t)g0 * DIM + c);
  bf16x4 b = *(const bf16x4*)(eout + (size_t)g1 * DIM + c);
  float4 o;
  o.x = (float)a[0] + (float)b[0];
  o.y = (float)a[1] + (float)b[1];
  o.z = (float)a[2] + (float)b[2];
  o.w = (float)a[3] + (float)b[3];
  *(float4*)(out + (size_t)t * DIM + c) = o;
}

extern "C" void kernel_launch(void* const* d_in, const int* in_sizes, int n_in,
                              void* d_out, int out_size, void* d_ws, size_t ws_size,
                              hipStream_t stream) {
  const float* x   = (const float*)d_in[0];
  const float* rw  = (const float*)d_in[1];
  const float* rb  = (const float*)d_in[2];
  const float* w12 = (const float*)d_in[3];
  const float* w3  = (const float*)d_in[4];
  float* out = (float*)d_out;
  float* aux = out + (size_t)T_TOK * DIM;

  char* ws = (char*)d_ws;
  int*   counts     = (int*)(ws + 0);
  int*   fill       = (int*)(ws + 64);
  int*   base       = (int*)(ws + 128);
  int*   top_i      = (int*)(ws + 4096);
  float* top_w      = (float*)(ws + 4096 + 32768);
  int*   slot_token = (int*)(ws + 4096 + 65536);
  float* slot_wt    = (float*)(ws + 4096 + 98304);
  int*   slot_of    = (int*)(ws + 4096 + 131072);
  int*   tile_e     = (int*)(ws + 4096 + 163840);
  int*   tile_m0    = (int*)(ws + 4096 + 164352);
  bf16_t* xb        = (bf16_t*)(ws + 262144);                       // 8 MiB
  bf16_t* h         = (bf16_t*)(ws + 262144 + 8388608);             // 32 MiB
  bf16_t* eout      = (bf16_t*)(ws + 262144 + 8388608 + 33554432);  // 16 MiB
  // peak ws ≈ 58 MiB (no weight copies at all)

  hipMemsetAsync(ws, 0, 256, stream);                 // counts/fill
  hipMemsetAsync(aux, 0, sizeof(float), stream);      // aux accumulator

  k_router<<<dim3(T_TOK / 4), dim3(256), 0, stream>>>(x, rw, rb, counts, top_i, top_w,
                                                      aux, xb);
  k_plan<<<dim3(1), dim3(64), 0, stream>>>(counts, base, tile_e, tile_m0);
  k_gather<<<dim3(T_TOK / 256), dim3(256), 0, stream>>>(top_i, top_w, base, fill,
                                                        slot_token, slot_wt, slot_of);
  k_gemm1<<<dim3(HID / 64, MAXT), dim3(256), 0, stream>>>(
      xb, w12, counts, base, tile_e, tile_m0, slot_token, h);
  k_gemm2<<<dim3(DIM / 128, MAXT), dim3(256), 0, stream>>>(
      h, w3, counts, base, tile_e, tile_m0, slot_wt, eout);
  k_combine<<<dim3(T_TOK), dim3(256), 0, stream>>>(eout, slot_of, out);
}